// Round 11
// baseline (143.244 us; speedup 1.0000x reference)
//
#include <hip/hip_runtime.h>
#include <hip/hip_bf16.h>

#define B_N 8192
#define D_K 256
#define BM  256
#define BN  32
#define JSPLIT 32
#define JSPAN (B_N / JSPLIT)     // 256
#define NTILE (JSPAN / BN)       // 8
#define INVT 14.285714285714286f
#define C1   20.60992907f        // INVT * log2(e)

typedef __bf16 bf16x8 __attribute__((ext_vector_type(8)));
typedef float  f32x16 __attribute__((ext_vector_type(16)));
typedef float  f32x4  __attribute__((ext_vector_type(4)));

#define AS1 __attribute__((address_space(1)))
#define AS3 __attribute__((address_space(3)))

__device__ __forceinline__ unsigned short f32_to_bf16_rne(float f) {
    unsigned int u = __float_as_uint(f);
    unsigned int r = (u + 0x7FFFu + ((u >> 16) & 1u)) >> 16;
    return (unsigned short)r;
}
__device__ __forceinline__ float bf16_to_f32(unsigned short u) {
    return __uint_as_float(((unsigned int)u) << 16);
}

// grid 2048 x 256: one wave per row. float4 loads, shfl reduce, bf16 store.
// Block 0 thread 0 zeroes the output accumulator (re-poisoned every launch).
__global__ void norm_kernel(const float* __restrict__ emb,
                            unsigned short* __restrict__ en,
                            float* __restrict__ out) {
    const int t = threadIdx.x;
    const int w = t >> 6, l = t & 63;
    const int row = blockIdx.x * 4 + w;
    if (blockIdx.x == 0 && t == 0) out[0] = 0.0f;
    f32x4 x = *reinterpret_cast<const f32x4*>(emb + (size_t)row * D_K + l * 4);
    float ss = x[0]*x[0] + x[1]*x[1] + x[2]*x[2] + x[3]*x[3];
    #pragma unroll
    for (int m = 1; m < 64; m <<= 1) ss += __shfl_xor(ss, m, 64);
    float sc = 1.0f / fmaxf(sqrtf(ss), 1e-12f);
    ushort4 o;
    o.x = f32_to_bf16_rne(x[0] * sc); o.y = f32_to_bf16_rne(x[1] * sc);
    o.z = f32_to_bf16_rne(x[2] * sc); o.w = f32_to_bf16_rne(x[3] * sc);
    *reinterpret_cast<ushort4*>(en + (size_t)row * D_K + l * 4) = o;
}

// Pure softmax-denominator GEMM: no labels in the hot loop at all.
// BM=256 (wave w owns 64 i-rows as two 32-row MFMA chains sharing each
// A-read -- halves the LDS-read pipe), BN=32 j-tiles, 2-buffer LDS (32 KB).
// Grid 1024 (32 itiles x 32 jsplits). XCD swizzle: each XCD owns 4 itiles
// (512 KB, L2-resident) x all 32 jsplits.
__launch_bounds__(256, 2)
__global__ void loss_kernel(const unsigned short* __restrict__ en,
                            float* __restrict__ s_part) {
    __shared__ __align__(16) unsigned short Bls[2][BN * D_K];  // 2 x 16 KB

    const int t  = threadIdx.x;
    const int l  = t & 63;
    const int w  = t >> 6;
    const int ir = l & 31;
    const int h  = l >> 5;

    // itile-major XCD swizzle: xcd owns itiles [4*xcd, 4*xcd+4), all jsplits
    const int b      = blockIdx.x;
    const int xcd    = b & 7;
    const int local  = b >> 3;               // [0,128)
    const int itile  = xcd * 4 + (local & 3);
    const int jsplit = local >> 2;           // [0,32)
    const int ibase  = itile * BM;
    const int j0     = jsplit * JSPAN;

    // resident i-side fragments: two 32-row chains, 16 ks-slices each
    bf16x8 bi0[16], bi1[16];
    {
        const unsigned short* ap0 =
            en + (size_t)(ibase + w * 64 + ir) * D_K + h * 8;
        const unsigned short* ap1 = ap0 + 32 * D_K;
        #pragma unroll
        for (int ks = 0; ks < 16; ++ks) {
            bi0[ks] = *reinterpret_cast<const bf16x8*>(ap0 + ks * 16);
            bi1[ks] = *reinterpret_cast<const bf16x8*>(ap1 + ks * 16);
        }
    }

    // hoisted staging addresses (srcm rd-invariant: rd steps rows by 8)
    const int srcm = (t & 31) ^ ((t >> 5) & 7);
    const unsigned short* gb =
        en + (size_t)(j0 + (t >> 5)) * D_K + srcm * 8;
    const char* abase0 = (const char*)Bls[0] + (size_t)ir * 512;
    const char* abase1 = (const char*)Bls[1] + (size_t)ir * 512;
    const int xr = (ir & 7) << 4;

    float sA0 = 0.f, sA1 = 0.f, sB0 = 0.f, sB1 = 0.f;

#define STAGE(bufp, itv)                                                     \
    {                                                                        \
        const unsigned short* gsrc = gb + (size_t)(itv) * (BN * D_K);        \
        char* ldst = (char*)(bufp) + t * 16;                                 \
        _Pragma("unroll")                                                    \
        for (int rd = 0; rd < 4; ++rd)                                       \
            __builtin_amdgcn_global_load_lds(                                \
                (const AS1 void*)(gsrc + rd * 2048),                         \
                (AS3 void*)(ldst + rd * 4096), 16, 0, 0);                    \
    }

#define TILE_COMPUTE(arow_b)                                                 \
    {                                                                        \
        f32x16 a0, a1;                                                       \
        _Pragma("unroll")                                                    \
        for (int q = 0; q < 16; ++q) { a0[q] = 0.0f; a1[q] = 0.0f; }         \
        __builtin_amdgcn_s_setprio(1);                                       \
        _Pragma("unroll")                                                    \
        for (int ks = 0; ks < 16; ++ks) {                                    \
            const bf16x8 af = *reinterpret_cast<const bf16x8*>(              \
                (arow_b) + ((((ks << 1) | h) << 4) ^ xr));                   \
            a0 = __builtin_amdgcn_mfma_f32_32x32x16_bf16(af, bi0[ks], a0,    \
                                                         0, 0, 0);           \
            a1 = __builtin_amdgcn_mfma_f32_32x32x16_bf16(af, bi1[ks], a1,    \
                                                         0, 0, 0);           \
        }                                                                    \
        __builtin_amdgcn_s_setprio(0);                                       \
        _Pragma("unroll")                                                    \
        for (int q = 0; q < 16; ++q) {                                       \
            float e0 = __builtin_amdgcn_exp2f(fmaf(a0[q], C1, -C1));         \
            float e1 = __builtin_amdgcn_exp2f(fmaf(a1[q], C1, -C1));         \
            if (q & 1) { sA1 += e0; sB1 += e1; }                             \
            else       { sA0 += e0; sB0 += e1; }                             \
        }                                                                    \
    }

    STAGE(Bls[0], 0);
    __syncthreads();

    for (int it = 0; it < NTILE; it += 2) {
        if (it + 1 < NTILE) STAGE(Bls[1], it + 1);
        TILE_COMPUTE(abase0);
        __syncthreads();
        if (it + 2 < NTILE) STAGE(Bls[0], it + 2);
        TILE_COMPUTE(abase1);
        __syncthreads();
    }
#undef STAGE
#undef TILE_COMPUTE

    // chains own distinct i-rows: halve-reduce, write per-split partials
    float sA = sA0 + sA1, sB = sB0 + sB1;
    sA += __shfl_xor(sA, 32, 64);
    sB += __shfl_xor(sB, 32, 64);
    if (h == 0) {
        const size_t base = (size_t)jsplit * B_N + ibase + w * 64 + ir;
        s_part[base]      = sA;
        s_part[base + 32] = sB;
    }
}

// grid 2048 x 256: one wave per row i. Positives are sparse (avg 8/row):
// scan all labels from LDS via ballot, compute each positive's dot directly
// (wave-parallel 256-dim dot + shfl reduce). Exact ps/pc, no histogram,
// no atomics, no self-term correction (j==i skipped explicitly).
__global__ void final_kernel(const unsigned short* __restrict__ en,
                             const int* __restrict__ labels,
                             const float* __restrict__ s_part,
                             float* __restrict__ out) {
    __shared__ __align__(16) int Lab_s[B_N];   // 32 KB
    __shared__ float part[4];

    const int t = threadIdx.x, w = t >> 6, l = t & 63;
    const int i = blockIdx.x * 4 + w;

    #pragma unroll
    for (int k = 0; k < B_N / 256; ++k)
        Lab_s[t + k * 256] = labels[t + k * 256];
    __syncthreads();

    // cache en_i: 4 elements per lane
    float ei[4];
    {
        ushort4 eu =
            *reinterpret_cast<const ushort4*>(en + (size_t)i * D_K + l * 4);
        ei[0] = bf16_to_f32(eu.x); ei[1] = bf16_to_f32(eu.y);
        ei[2] = bf16_to_f32(eu.z); ei[3] = bf16_to_f32(eu.w);
    }
    const int li = Lab_s[i];

    float ps = 0.0f;
    int   pcnt = 0;
    for (int c = 0; c < B_N / 64; ++c) {
        int lj = Lab_s[c * 64 + l];
        unsigned long long m = __ballot(lj == li);
        pcnt += __popcll(m);
        while (m) {
            int js = __ffsll((long long)m) - 1;
            m &= m - 1;
            int j = c * 64 + js;
            if (j != i) {
                ushort4 eu = *reinterpret_cast<const ushort4*>(
                    en + (size_t)j * D_K + l * 4);
                float d = ei[0] * bf16_to_f32(eu.x)
                        + ei[1] * bf16_to_f32(eu.y)
                        + ei[2] * bf16_to_f32(eu.z)
                        + ei[3] * bf16_to_f32(eu.w);
                #pragma unroll
                for (int mm = 1; mm < 64; mm <<= 1) d += __shfl_xor(d, mm, 64);
                ps += d;
            }
        }
    }
    pcnt -= 1;   // self always matches

    // softmax denominator: 32 per-split partials, one per lane<32
    float sv = (l < 32) ? s_part[(size_t)l * B_N + i] : 0.0f;
    #pragma unroll
    for (int mm = 1; mm < 64; mm <<= 1) sv += __shfl_xor(sv, mm, 64);

    if (l == 0) {
        float loss = (pcnt > 0)
            ? (INVT + logf(sv)) - ps * INVT / (float)pcnt : 0.0f;
        part[w] = loss;
    }
    __syncthreads();
    if (t == 0)
        atomicAdd(out, (part[0] + part[1] + part[2] + part[3]) * (1.0f / B_N));
}

extern "C" void kernel_launch(void* const* d_in, const int* in_sizes, int n_in,
                              void* d_out, int out_size, void* d_ws, size_t ws_size,
                              hipStream_t stream) {
    const float* emb    = (const float*)d_in[0];
    const int*   labels = (const int*)d_in[1];
    float*       out    = (float*)d_out;

    unsigned short* en = (unsigned short*)d_ws;                     // 4 MB
    float* s_part = (float*)((char*)d_ws + (size_t)B_N * D_K * 2);  // 1 MB

    hipLaunchKernelGGL(norm_kernel, dim3(B_N / 4), dim3(256), 0, stream,
                       emb, en, out);
    hipLaunchKernelGGL(loss_kernel, dim3((B_N / BM) * JSPLIT), dim3(256), 0,
                       stream, en, s_part);
    hipLaunchKernelGGL(final_kernel, dim3(B_N / 4), dim3(256), 0, stream,
                       en, labels, s_part, out);
}